// Round 24
// baseline (120.412 us; speedup 1.0000x reference)
//
#include <hip/hip_runtime.h>
#include <hip/hip_fp16.h>
#include <math.h>

// TreeBackbone — round 24 = round 23 with ONE change: build phase emits ONE
// b128 per task (quad-granular, 960 tasks/g) at contiguous 16B stride ->
// conflict-free writes. r23's 32B-stride task writes were a 16-way bank
// conflict (SQ_LDS_BANK_CONFLICT constant 8.09M = ~13us/CU since r13).
// cvtpk total unchanged; s_W layout unchanged (read side untouched).

#define NTW   (21 * 15 * 16 * 32)
#define TWBYTES (NTW * 2)
#define WFRAG_HALFS (3 * 2 * 64 * 8)
#define WFRAG_BYTES (WFRAG_HALFS * 2)
// pool: 315 chunk-planes x B images x 32 halfs (64B per (chunk,b))

typedef __fp16 h2v __attribute__((ext_vector_type(2)));
typedef short short8v __attribute__((ext_vector_type(8)));
typedef float float4v __attribute__((ext_vector_type(4)));
union HU { unsigned u; h2v v; };
union FRAG { uint4 u; short8v s; };

#if defined(__has_builtin)
#if __has_builtin(__builtin_amdgcn_fdot2)
#define HAVE_FDOT2 1
#endif
#endif

__device__ __forceinline__ float sigmoidf_(float v) {
    return 1.0f / (1.0f + __expf(-v));
}
__device__ __forceinline__ h2v as_h2(unsigned x) { HU t; t.u = x; return t.v; }
__device__ __forceinline__ ushort f2bf(float v) {
    unsigned u = __float_as_uint(v);
    u += 0x7fffu + ((u >> 16) & 1u);
    return (ushort)(u >> 16);
}
__device__ __forceinline__ unsigned cvtpk_bf16(float a, float b) {
    unsigned r;
    asm volatile("v_cvt_pk_bf16_f32 %0, %1, %2" : "=v"(r) : "v"(a), "v"(b));
    return r;
}
__device__ __forceinline__ unsigned pkrtz(float a, float b) {
    HU t; t.v = __builtin_amdgcn_cvt_pkrtz(a, b); return t.u;
}

// ---- merged prep (r23 verbatim) ----
__global__ __launch_bounds__(256) void prep_all(
    const float* __restrict__ tw, const float* __restrict__ cw,
    __half* __restrict__ tw2, ushort* __restrict__ wfrag)
{
    int i = blockIdx.x * 256 + threadIdx.x;
    if (i < NTW) {
        const int e   = i & 31;
        const int o   = (i >> 5) & 15;
        const int fgh = i >> 9;
        const int f   = fgh % 15, gh = fgh / 15;
        const int g   = gh / 7,  h  = gh % 7;
        const int parity = e >> 4, rem = e & 15, half = rem >> 3, pxl = rem & 7;
        float v = 0.f;
        if (pxl < 7) {
            const int px = half * 7 + pxl;
            const int w = px >> 1, j = px & 1;
            v = tw[o * 8820 + f * 588 + g * 196 + h * 28 + w * 4 + parity * 2 + j];
        }
        tw2[i] = __float2half(v);
        return;
    }
    const int j5 = i - NTW;
    if (j5 >= 384) return;
    const int g  = j5 >> 7, rem = j5 & 127, fr = rem >> 6, l = rem & 63;
    const int f  = l & 15, q = l >> 4;
    ushort o[8];
    #pragma unroll
    for (int j = 0; j < 8; ++j) {
        float v = 0.f;
        if (f < 15 && j < 5) {
            if (fr == 0)           v = cw[(g * 15 + f) * 25 + q * 5 + j];
            else if (q == 0)       v = cw[(g * 15 + f) * 25 + 20 + j];
        }
        o[j] = f2bf(v);
    }
    ushort* d = wfrag + ((g * 2 + fr) * 64 + l) * 8;
    *(uint4*)d = make_uint4(
        (unsigned)o[0] | ((unsigned)o[1] << 16),
        (unsigned)o[2] | ((unsigned)o[3] << 16),
        (unsigned)o[4] | ((unsigned)o[5] << 16),
        (unsigned)o[6] | ((unsigned)o[7] << 16));
}

// ---- kernel A: MFMA conv -> transposed pool flush; quad-granular build ----
__global__ __launch_bounds__(256, 5) void conv_pool_mfma(
    const float* __restrict__ x,
    const float* __restrict__ cb,
    const ushort* __restrict__ wfrag,
    __half* __restrict__ pool16,      // [315][B][32] f16
    int B)
{
    __shared__ __align__(16) float  s_xf[32 * 40];     // 5120 B g-plane
    __shared__ __align__(16) ushort s_W[32 * 30 * 8];  // 15360 B windows (one g)
    __shared__ __align__(16) ushort s_pool[105 * 40];  // 8400 B (one g's chunks)
    __shared__ float s_cb[45];
    __shared__ __align__(16) ushort s_zero[8];

    const int b = blockIdx.x;
    if (b >= B) return;
    const int t = threadIdx.x;
    const int lane = t & 63, wv = t >> 6;
    const int q = lane >> 4, oxl = lane & 15;

    if (t < 45) s_cb[t] = cb[t];
    if (t == 45) *(uint4*)&s_zero[0] = make_uint4(0u, 0u, 0u, 0u);

    const float4v z4 = {0.f, 0.f, 0.f, 0.f};
    const int row_s = t >> 3, q_s = t & 7;               // staging coords
    const uint4* wf4 = (const uint4*)wfrag;
    const float4* x4 = (const float4*)(x + (size_t)b * 3072);

    #pragma unroll                                        // static g
    for (int g = 0; g < 3; ++g) {
        FRAG w1g, w2g;
        w1g.u = wf4[(g * 2 + 0) * 64 + lane];
        w2g.u = wf4[(g * 2 + 1) * 64 + lane];
        const float4 xg = x4[g * 256 + t];

        // ---- stage g-plane + zero pads ----
        *(float4*)&s_xf[row_s * 40 + q_s * 4] = xg;
        if (t < 64) {
            const int r2 = t >> 1, k = t & 1;
            *(float4*)&s_xf[r2 * 40 + 32 + k * 4] = make_float4(0.f, 0.f, 0.f, 0.f);
        }
        __syncthreads();

        // ---- build windows: 960 quad-tasks = (row, OX); ONE b128 each ----
        // write addr = 16*qi (contiguous stride) -> conflict-free   [r24 FIX]
        #pragma unroll 1
        for (int qi = t; qi < 960; qi += 256) {
            const int row = qi / 30, OX = qi % 30;
            const int m = OX >> 1, par = OX & 1;
            const float* src = &s_xf[row * 40 + 2 * m];
            float f[10];
            #pragma unroll
            for (int k = 0; k < 5; ++k)
                *(float2*)&f[2 * k] = *(const float2*)&src[2 * k];
            uint4 qd;
            if (par == 0) {
                qd.x = cvtpk_bf16(f[0], f[1]); qd.y = cvtpk_bf16(f[2], f[3]);
                qd.z = cvtpk_bf16(f[4], f[5]); qd.w = cvtpk_bf16(f[6], f[7]);
            } else {
                qd.x = cvtpk_bf16(f[1], f[2]); qd.y = cvtpk_bf16(f[3], f[4]);
                qd.z = cvtpk_bf16(f[5], f[6]); qd.w = cvtpk_bf16(f[7], f[8]);
            }
            *(uint4*)&s_W[qi * 8] = qd;     // (row*30+OX)*8 halfs == qi*8
        }
        __syncthreads();

        // ---- main: 28 tile-pairs; wave wv owns 7 (math = r12..r23) ----
        #pragma unroll 1
        for (int i = 0; i < 7; ++i) {
            const int p = wv * 7 + i;
            const int py = p >> 1, half = p & 1;
            const ushort* base = &s_W[(2 * py + q) * 240 + (oxl + 14 * half) * 8];

            FRAG a10, a11, a20, a21;
            a10.u = *(const uint4*)base;
            a11.u = *(const uint4*)(base + 240);
            const ushort* p20 = (q == 0)
                ? &s_W[(2 * py + 4) * 240 + oxl * 8 + half * 112] : &s_zero[0];
            const ushort* p21 = (q == 0)
                ? &s_W[(2 * py + 5) * 240 + oxl * 8 + half * 112] : &s_zero[0];
            a20.u = *(const uint4*)p20;
            a21.u = *(const uint4*)p21;

            float4v acc0 = __builtin_amdgcn_mfma_f32_16x16x32_bf16(a20.s, w2g.s, z4, 0, 0, 0);
            acc0 = __builtin_amdgcn_mfma_f32_16x16x32_bf16(a10.s, w1g.s, acc0, 0, 0, 0);
            float4v acc1 = __builtin_amdgcn_mfma_f32_16x16x32_bf16(a21.s, w2g.s, z4, 0, 0, 0);
            acc1 = __builtin_amdgcn_mfma_f32_16x16x32_bf16(a11.s, w1g.s, acc1, 0, 0, 0);

            const int f = oxl;
            if (f < 15) {
                const float bias = s_cb[g * 15 + f];
                const float p0 = fmaxf(fmaxf(acc0[0], acc0[1]), fmaxf(acc1[0], acc1[1]));
                const float p1 = fmaxf(fmaxf(acc0[2], acc0[3]), fmaxf(acc1[2], acc1[3]));
                const float s0 = sigmoidf_(p0 + bias);
                const float s1 = (q < 3) ? sigmoidf_(p1 + bias) : 0.f;
                const int chunk = f * 7 + (py >> 1);             // local to g
                const int e0i = (py & 1) * 16 + half * 8 + 2 * q;
                *(unsigned*)&s_pool[chunk * 40 + e0i] = pkrtz(s0, s1);
            }
        }
        __syncthreads();

        // ---- per-g flush -> transposed planes (r23 verbatim) ----
        #pragma unroll 1
        for (int i = t; i < 420; i += 256) {
            const int chunk = i >> 2, k = i & 3;
            uint4* dst4 = (uint4*)(pool16
                + ((size_t)(g * 105 + chunk) * B + b) * 32);
            dst4[k] = *(const uint4*)&s_pool[chunk * 40 + k * 8];
        }
        __syncthreads();
    }
}

// ---- kernel B: tree, coalesced transposed-pool reads (r23 verbatim) ----
__global__ __launch_bounds__(256) void tree_kernel(
    const __half* __restrict__ pool16,  // [315][B][32]
    const __half* __restrict__ tw2,     // [gh][f][o][32] sigma
    const float* __restrict__ tb,
    float* __restrict__ out,
    int B, int nblk)
{
    __shared__ float s_red[256 * 17];

    const int cpx = nblk / 8;
    const int sid = (blockIdx.x % 8) * cpx + blockIdx.x / 8;
    const int gh = sid % 21, tile = sid / 21;
    const int g = gh / 7, h = gh % 7;

    const int t  = threadIdx.x;
    const int bl = t & 63, fg = t >> 6;
    const int b  = tile * 64 + bl;
    if (b >= B) return;

    const int f0 = fg * 4;
    const int nf = (fg < 3) ? 4 : 3;

    float acc[16];
    #pragma unroll
    for (int o = 0; o < 16; ++o) acc[o] = 0.f;

    #pragma unroll 1
    for (int fi = 0; fi < nf; ++fi) {
        const int f = f0 + fi;
        const uint4* pc = (const uint4*)(pool16
            + ((size_t)((g * 15 + f) * 7 + h) * B + b) * 32);
        const uint4* wc = (const uint4*)(tw2 + (size_t)((gh * 15 + f) * 16) * 32);
        uint4 pu[4];
        #pragma unroll
        for (int k = 0; k < 4; ++k) pu[k] = pc[k];
        #pragma unroll
        for (int o = 0; o < 16; ++o) {
            #pragma unroll
            for (int k = 0; k < 4; ++k) {
                const uint4 wu = wc[o * 4 + k];
#ifdef HAVE_FDOT2
                acc[o] = __builtin_amdgcn_fdot2(as_h2(pu[k].x), as_h2(wu.x), acc[o], false);
                acc[o] = __builtin_amdgcn_fdot2(as_h2(pu[k].y), as_h2(wu.y), acc[o], false);
                acc[o] = __builtin_amdgcn_fdot2(as_h2(pu[k].z), as_h2(wu.z), acc[o], false);
                acc[o] = __builtin_amdgcn_fdot2(as_h2(pu[k].w), as_h2(wu.w), acc[o], false);
#else
                const unsigned pw[4] = {pu[k].x, pu[k].y, pu[k].z, pu[k].w};
                const unsigned ww[4] = {wu.x, wu.y, wu.z, wu.w};
                #pragma unroll
                for (int qq = 0; qq < 4; ++qq) {
                    acc[o] += __half2float(__ushort_as_half((ushort)(pw[qq] & 0xffff)))
                            * __half2float(__ushort_as_half((ushort)(ww[qq] & 0xffff)));
                    acc[o] += __half2float(__ushort_as_half((ushort)(pw[qq] >> 16)))
                            * __half2float(__ushort_as_half((ushort)(ww[qq] >> 16)));
                }
#endif
            }
        }
    }

    #pragma unroll
    for (int o = 0; o < 16; ++o) s_red[t * 17 + o] = acc[o];
    __syncthreads();

    const int og = t >> 6;
    #pragma unroll
    for (int m = 0; m < 4; ++m) {
        const int o = og * 4 + m;
        float a = s_red[(0 * 64 + bl) * 17 + o] + s_red[(1 * 64 + bl) * 17 + o]
                + s_red[(2 * 64 + bl) * 17 + o] + s_red[(3 * 64 + bl) * 17 + o];
        const int idx = o * 21 + gh;
        out[(size_t)b * 336 + idx] = sigmoidf_(a + tb[idx]);
    }
}

// ---- fallback: round-2 fused kernel verbatim (fp32, known-good) ----
__global__ __launch_bounds__(256) void tree_backbone_legacy(
    const float* __restrict__ x, const float* __restrict__ cw,
    const float* __restrict__ cb, const float* __restrict__ tw,
    const float* __restrict__ tb, float* __restrict__ out, int B)
{
    __shared__ float s_x[3 * 32 * 36];
    __shared__ float s_cwl[45 * 25];
    __shared__ float s_cb[45];
    __shared__ float s_pool[45][197];

    const int b = blockIdx.x;
    if (b >= B) return;
    const int t = threadIdx.x;

    const float4* xs = (const float4*)(x + (size_t)b * 3072);
    for (int i = t; i < 768; i += 256) {
        const float4 v = xs[i];
        const int g = i >> 8, rem = i & 255, r = rem >> 3, qq = rem & 7;
        const int p = ((r & 1) << 4) + (r >> 1);
        *(float4*)&s_x[(g * 32 + p) * 36 + qq * 4] = v;
    }
    for (int i = t; i < 1125; i += 256) s_cwl[i] = cw[i];
    if (t < 45) s_cb[t] = cb[t];
    __syncthreads();

    for (int task = t; task < 1260; task += 256) {
        const int h  = (task >= 630) ? 1 : 0;
        const int tt = task - 630 * h;
        const int c  = tt / 14;
        const int py = tt - c * 14;
        const int g  = c / 15;
        float aA[14], aB[14];
        #pragma unroll
        for (int d = 0; d < 14; ++d) { aA[d] = 0.f; aB[d] = 0.f; }
        #pragma unroll
        for (int dr = 0; dr < 6; ++dr) {
            const float* rp = s_x + (g * 32 + ((dr & 1) << 4) + py + (dr >> 1)) * 36 + 12 * h;
            float f[20];
            #pragma unroll
            for (int k = 0; k < 5; ++k)
                *(float4*)&f[4 * k] = *(const float4*)&rp[4 * k];
            if (dr <= 4)
                #pragma unroll
                for (int kx = 0; kx < 5; ++kx) {
                    const float w = s_cwl[c * 25 + dr * 5 + kx];
                    #pragma unroll
                    for (int d = 0; d < 14; ++d) aA[d] += f[d + kx + 2 * h] * w;
                }
            if (dr >= 1)
                #pragma unroll
                for (int kx = 0; kx < 5; ++kx) {
                    const float w = s_cwl[c * 25 + (dr - 1) * 5 + kx];
                    #pragma unroll
                    for (int d = 0; d < 14; ++d) aB[d] += f[d + kx + 2 * h] * w;
                }
        }
        float* dst = &s_pool[c][py * 14 + 7 * h];
        #pragma unroll
        for (int p = 0; p < 7; ++p) {
            float m = fmaxf(fmaxf(aA[2 * p], aA[2 * p + 1]),
                            fmaxf(aB[2 * p], aB[2 * p + 1]));
            dst[p] = sigmoidf_(m + s_cb[c]);
        }
    }
    __syncthreads();

    for (int idx = t; idx < 336; idx += 256) {
        const int o  = idx / 21;
        const int r2 = idx - o * 21;
        const int g  = r2 / 7;
        const int hh = r2 - g * 7;
        const float* wp = tw + o * 8820 + g * 196 + hh * 28;
        float acc = 0.0f;
        #pragma unroll 1
        for (int f = 0; f < 15; ++f) {
            const float4* wf = (const float4*)(wp + f * 588);
            const float* p0 = &s_pool[g * 15 + f][(2 * hh) * 14];
            const float* p1 = p0 + 14;
            #pragma unroll
            for (int w = 0; w < 7; ++w) {
                const float4 qv = wf[w];
                acc += p0[2 * w] * qv.x + p0[2 * w + 1] * qv.y
                     + p1[2 * w] * qv.z + p1[2 * w + 1] * qv.w;
            }
        }
        out[(size_t)b * 336 + idx] = sigmoidf_(acc + tb[idx]);
    }
}

extern "C" void kernel_launch(void* const* d_in, const int* in_sizes, int n_in,
                              void* d_out, int out_size, void* d_ws, size_t ws_size,
                              hipStream_t stream) {
    const float* x  = (const float*)d_in[0];
    const float* cw = (const float*)d_in[1];
    const float* cb = (const float*)d_in[2];
    const float* tw = (const float*)d_in[3];
    const float* tb = (const float*)d_in[4];
    float* out = (float*)d_out;

    const int B = in_sizes[0] / 3072;   // 4096
    const size_t pool_bytes = (size_t)315 * B * 32 * 2;   // 82.6 MB
    const size_t need = (size_t)TWBYTES + (size_t)WFRAG_BYTES + pool_bytes;
    if (ws_size >= need) {
        __half* tw2    = (__half*)d_ws;
        ushort* wfrag  = (ushort*)((char*)d_ws + TWBYTES);
        __half* pool16 = (__half*)((char*)d_ws + TWBYTES + WFRAG_BYTES);
        const int nblk = (B / 64) * 21;
        prep_all<<<(NTW + 384 + 255) / 256, 256, 0, stream>>>(tw, cw, tw2, wfrag);
        conv_pool_mfma<<<B, 256, 0, stream>>>(x, cb, wfrag, pool16, B);
        tree_kernel<<<nblk, 256, 0, stream>>>(pool16, tw2, tb, out, B, nblk);
    } else {
        tree_backbone_legacy<<<B, 256, 0, stream>>>(x, cw, cb, tw, tb, out, B);
    }
}

// Round 25
// 114.901 us; speedup vs baseline: 1.0480x; 1.0480x over previous
//
#include <hip/hip_runtime.h>
#include <hip/hip_fp16.h>
#include <math.h>

// TreeBackbone — round 25 = round 23 (r24's build change reverted: it didn't
// touch the conflict counter and cost 5us) + ONE change: s_xf and s_pool are
// UNIONED (disjoint lifetimes, separated by the existing per-phase barriers:
// stage->bar->build(reads xf)->bar->main(writes pool)->bar->flush(reads pool)
// ->bar->next stage). LDS 29.2->24.0KB -> 6 blocks/CU; launch_bounds(256,6).

#define NTW   (21 * 15 * 16 * 32)
#define TWBYTES (NTW * 2)
#define WFRAG_HALFS (3 * 2 * 64 * 8)
#define WFRAG_BYTES (WFRAG_HALFS * 2)
// pool: 315 chunk-planes x B images x 32 halfs (64B per (chunk,b))

typedef __fp16 h2v __attribute__((ext_vector_type(2)));
typedef short short8v __attribute__((ext_vector_type(8)));
typedef float float4v __attribute__((ext_vector_type(4)));
union HU { unsigned u; h2v v; };
union FRAG { uint4 u; short8v s; };

#if defined(__has_builtin)
#if __has_builtin(__builtin_amdgcn_fdot2)
#define HAVE_FDOT2 1
#endif
#endif

__device__ __forceinline__ float sigmoidf_(float v) {
    return 1.0f / (1.0f + __expf(-v));
}
__device__ __forceinline__ h2v as_h2(unsigned x) { HU t; t.u = x; return t.v; }
__device__ __forceinline__ ushort f2bf(float v) {
    unsigned u = __float_as_uint(v);
    u += 0x7fffu + ((u >> 16) & 1u);
    return (ushort)(u >> 16);
}
__device__ __forceinline__ unsigned cvtpk_bf16(float a, float b) {
    unsigned r;
    asm volatile("v_cvt_pk_bf16_f32 %0, %1, %2" : "=v"(r) : "v"(a), "v"(b));
    return r;
}
__device__ __forceinline__ unsigned pkrtz(float a, float b) {
    HU t; t.v = __builtin_amdgcn_cvt_pkrtz(a, b); return t.u;
}

// ---- merged prep (r23 verbatim) ----
__global__ __launch_bounds__(256) void prep_all(
    const float* __restrict__ tw, const float* __restrict__ cw,
    __half* __restrict__ tw2, ushort* __restrict__ wfrag)
{
    int i = blockIdx.x * 256 + threadIdx.x;
    if (i < NTW) {
        const int e   = i & 31;
        const int o   = (i >> 5) & 15;
        const int fgh = i >> 9;
        const int f   = fgh % 15, gh = fgh / 15;
        const int g   = gh / 7,  h  = gh % 7;
        const int parity = e >> 4, rem = e & 15, half = rem >> 3, pxl = rem & 7;
        float v = 0.f;
        if (pxl < 7) {
            const int px = half * 7 + pxl;
            const int w = px >> 1, j = px & 1;
            v = tw[o * 8820 + f * 588 + g * 196 + h * 28 + w * 4 + parity * 2 + j];
        }
        tw2[i] = __float2half(v);
        return;
    }
    const int j5 = i - NTW;
    if (j5 >= 384) return;
    const int g  = j5 >> 7, rem = j5 & 127, fr = rem >> 6, l = rem & 63;
    const int f  = l & 15, q = l >> 4;
    ushort o[8];
    #pragma unroll
    for (int j = 0; j < 8; ++j) {
        float v = 0.f;
        if (f < 15 && j < 5) {
            if (fr == 0)           v = cw[(g * 15 + f) * 25 + q * 5 + j];
            else if (q == 0)       v = cw[(g * 15 + f) * 25 + 20 + j];
        }
        o[j] = f2bf(v);
    }
    ushort* d = wfrag + ((g * 2 + fr) * 64 + l) * 8;
    *(uint4*)d = make_uint4(
        (unsigned)o[0] | ((unsigned)o[1] << 16),
        (unsigned)o[2] | ((unsigned)o[3] << 16),
        (unsigned)o[4] | ((unsigned)o[5] << 16),
        (unsigned)o[6] | ((unsigned)o[7] << 16));
}

// ---- kernel A: MFMA conv; s_xf/s_pool unioned (r25) ----
__global__ __launch_bounds__(256, 6) void conv_pool_mfma(
    const float* __restrict__ x,
    const float* __restrict__ cb,
    const ushort* __restrict__ wfrag,
    __half* __restrict__ pool16,      // [315][B][32] f16
    int B)
{
    __shared__ __align__(16) char   s_u[8400];         // union: s_xf | s_pool
    __shared__ __align__(16) ushort s_W[32 * 30 * 8];  // 15360 B windows (one g)
    __shared__ float s_cb[45];
    __shared__ __align__(16) ushort s_zero[8];
    float*  s_xf   = (float*)s_u;                      // [32][40]  5120 B
    ushort* s_pool = (ushort*)s_u;                     // [105][40] 8400 B

    const int b = blockIdx.x;
    if (b >= B) return;
    const int t = threadIdx.x;
    const int lane = t & 63, wv = t >> 6;
    const int q = lane >> 4, oxl = lane & 15;

    if (t < 45) s_cb[t] = cb[t];
    if (t == 45) *(uint4*)&s_zero[0] = make_uint4(0u, 0u, 0u, 0u);

    const float4v z4 = {0.f, 0.f, 0.f, 0.f};
    const int row_s = t >> 3, q_s = t & 7;               // staging coords
    const uint4* wf4 = (const uint4*)wfrag;
    const float4* x4 = (const float4*)(x + (size_t)b * 3072);

    #pragma unroll                                        // static g
    for (int g = 0; g < 3; ++g) {
        FRAG w1g, w2g;
        w1g.u = wf4[(g * 2 + 0) * 64 + lane];
        w2g.u = wf4[(g * 2 + 1) * 64 + lane];
        const float4 xg = x4[g * 256 + t];

        // ---- stage g-plane + zero pads ----
        *(float4*)&s_xf[row_s * 40 + q_s * 4] = xg;
        if (t < 64) {
            const int r2 = t >> 1, k = t & 1;
            *(float4*)&s_xf[r2 * 40 + 32 + k * 4] = make_float4(0.f, 0.f, 0.f, 0.f);
        }
        __syncthreads();

        // ---- build windows: 480 tasks = (row, m) -> OX 2m, 2m+1 ----
        #pragma unroll 1
        for (int task = t; task < 480; task += 256) {
            const int row = task / 15, m = task % 15;
            const float* src = &s_xf[row * 40 + 2 * m];
            float f[10];
            #pragma unroll
            for (int k = 0; k < 5; ++k)
                *(float2*)&f[2 * k] = *(const float2*)&src[2 * k];
            const unsigned e0 = cvtpk_bf16(f[0], f[1]), e1 = cvtpk_bf16(f[2], f[3]);
            const unsigned e2 = cvtpk_bf16(f[4], f[5]), e3 = cvtpk_bf16(f[6], f[7]);
            const unsigned o0 = cvtpk_bf16(f[1], f[2]), o1 = cvtpk_bf16(f[3], f[4]);
            const unsigned o2 = cvtpk_bf16(f[5], f[6]), o3 = cvtpk_bf16(f[7], f[8]);
            ushort* wb = &s_W[(row * 30 + 2 * m) * 8];
            *(uint4*)wb       = make_uint4(e0, e1, e2, e3);
            *(uint4*)(wb + 8) = make_uint4(o0, o1, o2, o3);
        }
        __syncthreads();

        // ---- main: 28 tile-pairs; wave wv owns 7 (math = r12..r23) ----
        #pragma unroll 1
        for (int i = 0; i < 7; ++i) {
            const int p = wv * 7 + i;
            const int py = p >> 1, half = p & 1;
            const ushort* base = &s_W[(2 * py + q) * 240 + (oxl + 14 * half) * 8];

            FRAG a10, a11, a20, a21;
            a10.u = *(const uint4*)base;
            a11.u = *(const uint4*)(base + 240);
            const ushort* p20 = (q == 0)
                ? &s_W[(2 * py + 4) * 240 + oxl * 8 + half * 112] : &s_zero[0];
            const ushort* p21 = (q == 0)
                ? &s_W[(2 * py + 5) * 240 + oxl * 8 + half * 112] : &s_zero[0];
            a20.u = *(const uint4*)p20;
            a21.u = *(const uint4*)p21;

            float4v acc0 = __builtin_amdgcn_mfma_f32_16x16x32_bf16(a20.s, w2g.s, z4, 0, 0, 0);
            acc0 = __builtin_amdgcn_mfma_f32_16x16x32_bf16(a10.s, w1g.s, acc0, 0, 0, 0);
            float4v acc1 = __builtin_amdgcn_mfma_f32_16x16x32_bf16(a21.s, w2g.s, z4, 0, 0, 0);
            acc1 = __builtin_amdgcn_mfma_f32_16x16x32_bf16(a11.s, w1g.s, acc1, 0, 0, 0);

            const int f = oxl;
            if (f < 15) {
                const float bias = s_cb[g * 15 + f];
                const float p0 = fmaxf(fmaxf(acc0[0], acc0[1]), fmaxf(acc1[0], acc1[1]));
                const float p1 = fmaxf(fmaxf(acc0[2], acc0[3]), fmaxf(acc1[2], acc1[3]));
                const float s0 = sigmoidf_(p0 + bias);
                const float s1 = (q < 3) ? sigmoidf_(p1 + bias) : 0.f;
                const int chunk = f * 7 + (py >> 1);             // local to g
                const int e0i = (py & 1) * 16 + half * 8 + 2 * q;
                *(unsigned*)&s_pool[chunk * 40 + e0i] = pkrtz(s0, s1);
            }
        }
        __syncthreads();

        // ---- per-g flush -> transposed planes (r23 verbatim) ----
        #pragma unroll 1
        for (int i = t; i < 420; i += 256) {
            const int chunk = i >> 2, k = i & 3;
            uint4* dst4 = (uint4*)(pool16
                + ((size_t)(g * 105 + chunk) * B + b) * 32);
            dst4[k] = *(const uint4*)&s_pool[chunk * 40 + k * 8];
        }
        __syncthreads();
    }
}

// ---- kernel B: tree, coalesced transposed-pool reads (r23 verbatim) ----
__global__ __launch_bounds__(256) void tree_kernel(
    const __half* __restrict__ pool16,  // [315][B][32]
    const __half* __restrict__ tw2,     // [gh][f][o][32] sigma
    const float* __restrict__ tb,
    float* __restrict__ out,
    int B, int nblk)
{
    __shared__ float s_red[256 * 17];

    const int cpx = nblk / 8;
    const int sid = (blockIdx.x % 8) * cpx + blockIdx.x / 8;
    const int gh = sid % 21, tile = sid / 21;
    const int g = gh / 7, h = gh % 7;

    const int t  = threadIdx.x;
    const int bl = t & 63, fg = t >> 6;
    const int b  = tile * 64 + bl;
    if (b >= B) return;

    const int f0 = fg * 4;
    const int nf = (fg < 3) ? 4 : 3;

    float acc[16];
    #pragma unroll
    for (int o = 0; o < 16; ++o) acc[o] = 0.f;

    #pragma unroll 1
    for (int fi = 0; fi < nf; ++fi) {
        const int f = f0 + fi;
        const uint4* pc = (const uint4*)(pool16
            + ((size_t)((g * 15 + f) * 7 + h) * B + b) * 32);
        const uint4* wc = (const uint4*)(tw2 + (size_t)((gh * 15 + f) * 16) * 32);
        uint4 pu[4];
        #pragma unroll
        for (int k = 0; k < 4; ++k) pu[k] = pc[k];
        #pragma unroll
        for (int o = 0; o < 16; ++o) {
            #pragma unroll
            for (int k = 0; k < 4; ++k) {
                const uint4 wu = wc[o * 4 + k];
#ifdef HAVE_FDOT2
                acc[o] = __builtin_amdgcn_fdot2(as_h2(pu[k].x), as_h2(wu.x), acc[o], false);
                acc[o] = __builtin_amdgcn_fdot2(as_h2(pu[k].y), as_h2(wu.y), acc[o], false);
                acc[o] = __builtin_amdgcn_fdot2(as_h2(pu[k].z), as_h2(wu.z), acc[o], false);
                acc[o] = __builtin_amdgcn_fdot2(as_h2(pu[k].w), as_h2(wu.w), acc[o], false);
#else
                const unsigned pw[4] = {pu[k].x, pu[k].y, pu[k].z, pu[k].w};
                const unsigned ww[4] = {wu.x, wu.y, wu.z, wu.w};
                #pragma unroll
                for (int qq = 0; qq < 4; ++qq) {
                    acc[o] += __half2float(__ushort_as_half((ushort)(pw[qq] & 0xffff)))
                            * __half2float(__ushort_as_half((ushort)(ww[qq] & 0xffff)));
                    acc[o] += __half2float(__ushort_as_half((ushort)(pw[qq] >> 16)))
                            * __half2float(__ushort_as_half((ushort)(ww[qq] >> 16)));
                }
#endif
            }
        }
    }

    #pragma unroll
    for (int o = 0; o < 16; ++o) s_red[t * 17 + o] = acc[o];
    __syncthreads();

    const int og = t >> 6;
    #pragma unroll
    for (int m = 0; m < 4; ++m) {
        const int o = og * 4 + m;
        float a = s_red[(0 * 64 + bl) * 17 + o] + s_red[(1 * 64 + bl) * 17 + o]
                + s_red[(2 * 64 + bl) * 17 + o] + s_red[(3 * 64 + bl) * 17 + o];
        const int idx = o * 21 + gh;
        out[(size_t)b * 336 + idx] = sigmoidf_(a + tb[idx]);
    }
}

// ---- fallback: round-2 fused kernel verbatim (fp32, known-good) ----
__global__ __launch_bounds__(256) void tree_backbone_legacy(
    const float* __restrict__ x, const float* __restrict__ cw,
    const float* __restrict__ cb, const float* __restrict__ tw,
    const float* __restrict__ tb, float* __restrict__ out, int B)
{
    __shared__ float s_x[3 * 32 * 36];
    __shared__ float s_cwl[45 * 25];
    __shared__ float s_cb[45];
    __shared__ float s_pool[45][197];

    const int b = blockIdx.x;
    if (b >= B) return;
    const int t = threadIdx.x;

    const float4* xs = (const float4*)(x + (size_t)b * 3072);
    for (int i = t; i < 768; i += 256) {
        const float4 v = xs[i];
        const int g = i >> 8, rem = i & 255, r = rem >> 3, qq = rem & 7;
        const int p = ((r & 1) << 4) + (r >> 1);
        *(float4*)&s_x[(g * 32 + p) * 36 + qq * 4] = v;
    }
    for (int i = t; i < 1125; i += 256) s_cwl[i] = cw[i];
    if (t < 45) s_cb[t] = cb[t];
    __syncthreads();

    for (int task = t; task < 1260; task += 256) {
        const int h  = (task >= 630) ? 1 : 0;
        const int tt = task - 630 * h;
        const int c  = tt / 14;
        const int py = tt - c * 14;
        const int g  = c / 15;
        float aA[14], aB[14];
        #pragma unroll
        for (int d = 0; d < 14; ++d) { aA[d] = 0.f; aB[d] = 0.f; }
        #pragma unroll
        for (int dr = 0; dr < 6; ++dr) {
            const float* rp = s_x + (g * 32 + ((dr & 1) << 4) + py + (dr >> 1)) * 36 + 12 * h;
            float f[20];
            #pragma unroll
            for (int k = 0; k < 5; ++k)
                *(float4*)&f[4 * k] = *(const float4*)&rp[4 * k];
            if (dr <= 4)
                #pragma unroll
                for (int kx = 0; kx < 5; ++kx) {
                    const float w = s_cwl[c * 25 + dr * 5 + kx];
                    #pragma unroll
                    for (int d = 0; d < 14; ++d) aA[d] += f[d + kx + 2 * h] * w;
                }
            if (dr >= 1)
                #pragma unroll
                for (int kx = 0; kx < 5; ++kx) {
                    const float w = s_cwl[c * 25 + (dr - 1) * 5 + kx];
                    #pragma unroll
                    for (int d = 0; d < 14; ++d) aB[d] += f[d + kx + 2 * h] * w;
                }
        }
        float* dst = &s_pool[c][py * 14 + 7 * h];
        #pragma unroll
        for (int p = 0; p < 7; ++p) {
            float m = fmaxf(fmaxf(aA[2 * p], aA[2 * p + 1]),
                            fmaxf(aB[2 * p], aB[2 * p + 1]));
            dst[p] = sigmoidf_(m + s_cb[c]);
        }
    }
    __syncthreads();

    for (int idx = t; idx < 336; idx += 256) {
        const int o  = idx / 21;
        const int r2 = idx - o * 21;
        const int g  = r2 / 7;
        const int hh = r2 - g * 7;
        const float* wp = tw + o * 8820 + g * 196 + hh * 28;
        float acc = 0.0f;
        #pragma unroll 1
        for (int f = 0; f < 15; ++f) {
            const float4* wf = (const float4*)(wp + f * 588);
            const float* p0 = &s_pool[g * 15 + f][(2 * hh) * 14];
            const float* p1 = p0 + 14;
            #pragma unroll
            for (int w = 0; w < 7; ++w) {
                const float4 qv = wf[w];
                acc += p0[2 * w] * qv.x + p0[2 * w + 1] * qv.y
                     + p1[2 * w] * qv.z + p1[2 * w + 1] * qv.w;
            }
        }
        out[(size_t)b * 336 + idx] = sigmoidf_(acc + tb[idx]);
    }
}

extern "C" void kernel_launch(void* const* d_in, const int* in_sizes, int n_in,
                              void* d_out, int out_size, void* d_ws, size_t ws_size,
                              hipStream_t stream) {
    const float* x  = (const float*)d_in[0];
    const float* cw = (const float*)d_in[1];
    const float* cb = (const float*)d_in[2];
    const float* tw = (const float*)d_in[3];
    const float* tb = (const float*)d_in[4];
    float* out = (float*)d_out;

    const int B = in_sizes[0] / 3072;   // 4096
    const size_t pool_bytes = (size_t)315 * B * 32 * 2;   // 82.6 MB
    const size_t need = (size_t)TWBYTES + (size_t)WFRAG_BYTES + pool_bytes;
    if (ws_size >= need) {
        __half* tw2    = (__half*)d_ws;
        ushort* wfrag  = (ushort*)((char*)d_ws + TWBYTES);
        __half* pool16 = (__half*)((char*)d_ws + TWBYTES + WFRAG_BYTES);
        const int nblk = (B / 64) * 21;
        prep_all<<<(NTW + 384 + 255) / 256, 256, 0, stream>>>(tw, cw, tw2, wfrag);
        conv_pool_mfma<<<B, 256, 0, stream>>>(x, cb, wfrag, pool16, B);
        tree_kernel<<<nblk, 256, 0, stream>>>(pool16, tw2, tb, out, B, nblk);
    } else {
        tree_backbone_legacy<<<B, 256, 0, stream>>>(x, cw, cb, tw, tb, out, B);
    }
}